// Round 1
// baseline (1959.487 us; speedup 1.0000x reference)
//
#include <hip/hip_runtime.h>
#include <hip/hip_bf16.h>

#define BSz 2
#define Nn 15135
#define Ee 242160
#define F_INc 8
#define Hh 64
#define Ll 4
#define HFCc 256
#define NCc 10
#define EPSg 1e-15f

__global__ void deg_kernel(const int* __restrict__ dst, float* __restrict__ deg) {
    int e = blockIdx.x * blockDim.x + threadIdx.x;
    if (e < Ee) atomicAdd(&deg[dst[e]], 1.0f);
}

// hk[row, j] = sum_f in[row, f] * g[f, j]; one block per row (b*N+n), 128 threads
template<int F>
__global__ void transform_kernel(const float* __restrict__ in, const float* __restrict__ g,
                                 float* __restrict__ hk) {
    int row = blockIdx.x;
    int j = threadIdx.x;
    __shared__ float s_in[F];
    if (threadIdx.x < F) s_in[threadIdx.x] = in[row * F + threadIdx.x];
    __syncthreads();
    float acc = 0.f;
#pragma unroll
    for (int f = 0; f < F; ++f) acc += s_in[f] * g[f * 128 + j];
    hk[row * 128 + j] = acc;
}

// per (b, e, q): m[4] = gauss0*hk[src,q*4..] + gauss1*hk[src,64+q*4..]; atomicAdd to agg[dst]
__global__ void scatter_kernel(const float* __restrict__ hk, const int* __restrict__ src,
                               const int* __restrict__ dst, const float* __restrict__ pseudo,
                               const float* __restrict__ mu, const float* __restrict__ sigma,
                               float* __restrict__ agg) {
    int t = blockIdx.x * blockDim.x + threadIdx.x;
    int e = t >> 4, q = t & 15;
    if (e >= Ee) return;
    int b = blockIdx.y;
    float p0 = pseudo[e * 2 + 0], p1 = pseudo[e * 2 + 1];
    float d00 = p0 - mu[0], d01 = p1 - mu[1];
    float d10 = p0 - mu[2], d11 = p1 - mu[3];
    float i00 = 1.f / (EPSg + sigma[0] * sigma[0]);
    float i01 = 1.f / (EPSg + sigma[1] * sigma[1]);
    float i10 = 1.f / (EPSg + sigma[2] * sigma[2]);
    float i11 = 1.f / (EPSg + sigma[3] * sigma[3]);
    float g0 = expf(-0.5f * (d00 * d00 * i00 + d01 * d01 * i01));
    float g1 = expf(-0.5f * (d10 * d10 * i10 + d11 * d11 * i11));
    int s = src[e];
    const float* base = &hk[((size_t)b * Nn + s) * 128 + q * 4];
    float4 v0 = *(const float4*)(base);
    float4 v1 = *(const float4*)(base + 64);
    float* out = &agg[((size_t)b * Nn + dst[e]) * 64 + q * 4];
    atomicAdd(&out[0], g0 * v0.x + g1 * v1.x);
    atomicAdd(&out[1], g0 * v0.y + g1 * v1.y);
    atomicAdd(&out[2], g0 * v0.z + g1 * v1.z);
    atomicAdd(&out[3], g0 * v0.w + g1 * v1.w);
}

// one wave (64 lanes) per node row: val = agg/deg + prev@root + bias; ELU; also
// wave-reduce val*fc_w[h*L+l] into node accumulator.
template<int F>
__global__ void combine_kernel(const float* __restrict__ agg, const float* __restrict__ prev,
                               const float* __restrict__ root, const float* __restrict__ bias,
                               const float* __restrict__ deg, const float* __restrict__ fc_w,
                               int l, float* __restrict__ hout, float* __restrict__ node) {
    int tid = threadIdx.x;
    int lane = tid & 63;
    int n = blockIdx.x * 4 + (tid >> 6);
    int b = blockIdx.y;
    if (n >= Nn) return;
    size_t row = (size_t)b * Nn + n;
    float val = agg[row * 64 + lane] / fmaxf(deg[n], 1.0f);
    float rsum = 0.f;
#pragma unroll
    for (int f = 0; f < F; ++f) rsum += prev[row * F + f] * root[f * 64 + lane];
    val += rsum + bias[lane];
    val = val > 0.f ? val : expm1f(val);
    hout[row * 64 + lane] = val;
    float r = val * fc_w[lane * Ll + l];
#pragma unroll
    for (int off = 32; off; off >>= 1) r += __shfl_down(r, off, 64);
    if (lane == 0) node[row] += r;
}

// h1acc[b,hfc] += sum_{n in chunk} (node[b,n]+fc_b) * lin1_w[n,hfc]
__global__ void lin1_kernel(const float* __restrict__ node, const float* __restrict__ w,
                            const float* __restrict__ fcb, float* __restrict__ h1acc) {
    int hfc = threadIdx.x;
    int b = blockIdx.y;
    int n0 = blockIdx.x * 64;
    int nend = n0 + 64 < Nn ? n0 + 64 : Nn;
    float fb = fcb[0];
    float acc = 0.f;
    for (int n = n0; n < nend; ++n)
        acc += (node[(size_t)b * Nn + n] + fb) * w[(size_t)n * HFCc + hfc];
    atomicAdd(&h1acc[b * HFCc + hfc], acc);
}

__global__ void head_kernel(const float* __restrict__ h1acc, const float* __restrict__ l1b,
                            const float* __restrict__ w2, const float* __restrict__ b2,
                            float* __restrict__ out) {
    __shared__ float sh[HFCc];
    __shared__ float slog[NCc];
    __shared__ float s_lse;
    int tid = threadIdx.x;
    for (int b = 0; b < BSz; ++b) {
        float v = h1acc[b * HFCc + tid] + l1b[tid];
        v = v > 0.f ? v : expm1f(v);
        sh[tid] = v;
        __syncthreads();
        if (tid < NCc) {
            float s = b2[tid];
            for (int i = 0; i < HFCc; ++i) s += sh[i] * w2[i * NCc + tid];
            slog[tid] = s;
        }
        __syncthreads();
        if (tid == 0) {
            float m = slog[0];
            for (int c = 1; c < NCc; ++c) m = fmaxf(m, slog[c]);
            float se = 0.f;
            for (int c = 0; c < NCc; ++c) se += expf(slog[c] - m);
            s_lse = m + logf(se);
        }
        __syncthreads();
        if (tid < NCc) out[b * NCc + tid] = slog[tid] - s_lse;
        __syncthreads();
    }
}

extern "C" void kernel_launch(void* const* d_in, const int* in_sizes, int n_in,
                              void* d_out, int out_size, void* d_ws, size_t ws_size,
                              hipStream_t stream) {
    const float* x      = (const float*)d_in[0];
    const int*   ei     = (const int*)d_in[2];
    const float* pseudo = (const float*)d_in[3];
    const float* g1     = (const float*)d_in[4];
    const float* mu1    = (const float*)d_in[5];
    const float* sigma1 = (const float*)d_in[6];
    const float* root1  = (const float*)d_in[7];
    const float* b1     = (const float*)d_in[8];
    const float* gs     = (const float*)d_in[9];
    const float* mus    = (const float*)d_in[10];
    const float* sigmas = (const float*)d_in[11];
    const float* roots  = (const float*)d_in[12];
    const float* bs_p   = (const float*)d_in[13];
    const float* fc_w   = (const float*)d_in[14];
    const float* fc_b   = (const float*)d_in[15];
    const float* lin1_w = (const float*)d_in[16];
    const float* lin1_b = (const float*)d_in[17];
    const float* lin2_w = (const float*)d_in[18];
    const float* lin2_b = (const float*)d_in[19];
    float* out = (float*)d_out;

    const int* src = ei;
    const int* dst = ei + Ee;

    auto alignup = [](size_t x) { return (x + 255) & ~(size_t)255; };
    char* ws = (char*)d_ws;
    size_t off = 0;
    float* deg   = (float*)(ws + off); off += alignup((size_t)Nn * 4);
    float* node  = (float*)(ws + off); off += alignup((size_t)BSz * Nn * 4);
    float* h1acc = (float*)(ws + off); off += alignup((size_t)BSz * HFCc * 4);
    float* hk    = (float*)(ws + off); off += alignup((size_t)BSz * Nn * 128 * 4);
    float* agg   = (float*)(ws + off); off += alignup((size_t)BSz * Nn * 64 * 4);
    float* hA    = (float*)(ws + off); off += alignup((size_t)BSz * Nn * 64 * 4);
    float* hB    = (float*)(ws + off); off += alignup((size_t)BSz * Nn * 64 * 4);
    (void)ws_size; (void)in_sizes; (void)n_in; (void)out_size;

    hipMemsetAsync(deg, 0, (size_t)Nn * 4, stream);
    hipMemsetAsync(node, 0, (size_t)BSz * Nn * 4, stream);
    hipMemsetAsync(h1acc, 0, (size_t)BSz * HFCc * 4, stream);

    deg_kernel<<<(Ee + 255) / 256, 256, 0, stream>>>(dst, deg);

    const float* prev = x;
    float* hcur = hA;
    float* hnxt = hB;
    for (int l = 0; l < Ll; ++l) {
        const float* g  = (l == 0) ? g1     : gs     + (size_t)(l - 1) * Hh * 128;
        const float* mu = (l == 0) ? mu1    : mus    + (size_t)(l - 1) * 4;
        const float* sg = (l == 0) ? sigma1 : sigmas + (size_t)(l - 1) * 4;
        const float* rt = (l == 0) ? root1  : roots  + (size_t)(l - 1) * Hh * Hh;
        const float* bb = (l == 0) ? b1     : bs_p   + (size_t)(l - 1) * Hh;

        if (l == 0)
            transform_kernel<F_INc><<<BSz * Nn, 128, 0, stream>>>(prev, g, hk);
        else
            transform_kernel<Hh><<<BSz * Nn, 128, 0, stream>>>(prev, g, hk);

        hipMemsetAsync(agg, 0, (size_t)BSz * Nn * 64 * 4, stream);

        dim3 sgrid((Ee * 16 + 255) / 256, BSz);
        scatter_kernel<<<sgrid, 256, 0, stream>>>(hk, src, dst, pseudo, mu, sg, agg);

        dim3 cgrid((Nn + 3) / 4, BSz);
        if (l == 0)
            combine_kernel<F_INc><<<cgrid, 256, 0, stream>>>(agg, prev, rt, bb, deg, fc_w, l, hnxt, node);
        else
            combine_kernel<Hh><<<cgrid, 256, 0, stream>>>(agg, prev, rt, bb, deg, fc_w, l, hnxt, node);

        prev = hnxt;
        float* tmp = hcur; hcur = hnxt; hnxt = tmp;
    }

    dim3 lgrid((Nn + 63) / 64, BSz);
    lin1_kernel<<<lgrid, 256, 0, stream>>>(node, lin1_w, fc_b, h1acc);

    head_kernel<<<1, HFCc, 0, stream>>>(h1acc, lin1_b, lin2_w, lin2_b, out);
}

// Round 2
// 520.139 us; speedup vs baseline: 3.7672x; 3.7672x over previous
//
#include <hip/hip_runtime.h>
#include <hip/hip_bf16.h>

#define BSz 2
#define Nn 15135
#define Ee 242160
#define F_INc 8
#define Hh 64
#define Ll 4
#define HFCc 256
#define NCc 10
#define EPSg 1e-15f

// ---- CSR build ----------------------------------------------------------

__global__ void count_kernel(const int* __restrict__ dst, int* __restrict__ cnt) {
    int e = blockIdx.x * blockDim.x + threadIdx.x;
    if (e < Ee) atomicAdd(&cnt[dst[e]], 1);
}

// single-block exclusive scan over cnt[N] -> offs[N+1]
__global__ void scan_kernel(const int* __restrict__ cnt, int* __restrict__ offs) {
    __shared__ int s[256];
    int tid = threadIdx.x;
    int base = 0;
    for (int c0 = 0; c0 < Nn; c0 += 256) {
        int v = (c0 + tid < Nn) ? cnt[c0 + tid] : 0;
        s[tid] = v;
        __syncthreads();
        for (int d = 1; d < 256; d <<= 1) {
            int t = (tid >= d) ? s[tid - d] : 0;
            __syncthreads();
            s[tid] += t;
            __syncthreads();
        }
        if (c0 + tid < Nn) offs[c0 + tid] = base + s[tid] - v;  // exclusive
        base += s[255];
        __syncthreads();
    }
    if (tid == 0) offs[Nn] = base;
}

__global__ void copy_kernel(const int* __restrict__ offs, int* __restrict__ cursor) {
    int i = blockIdx.x * blockDim.x + threadIdx.x;
    if (i < Nn) cursor[i] = offs[i];
}

__global__ void fill_kernel(const int* __restrict__ src, const int* __restrict__ dst,
                            const float* __restrict__ pseudo, int* __restrict__ cursor,
                            int* __restrict__ csr_src, float2* __restrict__ csr_ps) {
    int e = blockIdx.x * blockDim.x + threadIdx.x;
    if (e >= Ee) return;
    int p = atomicAdd(&cursor[dst[e]], 1);
    csr_src[p] = src[e];
    csr_ps[p] = ((const float2*)pseudo)[e];
}

// Gaussian weights for all layers, in CSR order: gauss[l*E + p] = {g0, g1}
__global__ void gauss_kernel(const float2* __restrict__ csr_ps,
                             const float* __restrict__ mu1, const float* __restrict__ sigma1,
                             const float* __restrict__ mus, const float* __restrict__ sigmas,
                             float2* __restrict__ gauss) {
    int p = blockIdx.x * blockDim.x + threadIdx.x;
    if (p >= Ee) return;
    float2 ps = csr_ps[p];
#pragma unroll
    for (int l = 0; l < Ll; ++l) {
        const float* mu = (l == 0) ? mu1 : mus + (l - 1) * 4;
        const float* sg = (l == 0) ? sigma1 : sigmas + (l - 1) * 4;
        float d00 = ps.x - mu[0], d01 = ps.y - mu[1];
        float d10 = ps.x - mu[2], d11 = ps.y - mu[3];
        float i00 = 1.f / (EPSg + sg[0] * sg[0]);
        float i01 = 1.f / (EPSg + sg[1] * sg[1]);
        float i10 = 1.f / (EPSg + sg[2] * sg[2]);
        float i11 = 1.f / (EPSg + sg[3] * sg[3]);
        float g0 = expf(-0.5f * (d00 * d00 * i00 + d01 * d01 * i01));
        float g1 = expf(-0.5f * (d10 * d10 * i10 + d11 * d11 * i11));
        gauss[(size_t)l * Ee + p] = make_float2(g0, g1);
    }
}

// ---- per-layer compute ---------------------------------------------------

// hk2[row, c] = {hk_k0[c], hk_k1[c]} interleaved: thread j computes g-col j
// (j = k*64 + h) and writes slot row*128 + h*2 + k.
template<int F>
__global__ void transform_kernel(const float* __restrict__ in, const float* __restrict__ g,
                                 float* __restrict__ hk) {
    int row = blockIdx.x;
    int j = threadIdx.x;
    __shared__ float s_in[F];
    if (threadIdx.x < F) s_in[threadIdx.x] = in[row * F + threadIdx.x];
    __syncthreads();
    float acc = 0.f;
#pragma unroll
    for (int f = 0; f < F; ++f) acc += s_in[f] * g[f * 128 + j];
    int h = j & 63, k = j >> 6;
    hk[(size_t)row * 128 + h * 2 + k] = acc;
}

// one wave per (b, node): lane = output channel. Gather incoming edges via CSR,
// then /deg + prev@root + bias + ELU, write hout, wave-reduce into node acc.
template<int F>
__global__ void gather_combine(const float* __restrict__ hk, const int* __restrict__ offs,
                               const int* __restrict__ csr_src, const float2* __restrict__ gauss,
                               const float* __restrict__ prev, const float* __restrict__ root,
                               const float* __restrict__ bias, const float* __restrict__ fc_w,
                               int l, float* __restrict__ hout, float* __restrict__ node) {
    int tid = threadIdx.x;
    int lane = tid & 63;
    int n = blockIdx.x * 4 + (tid >> 6);
    int b = blockIdx.y;
    if (n >= Nn) return;
    int s0 = offs[n], s1 = offs[n + 1];
    const float2* hk2 = (const float2*)(hk + (size_t)b * Nn * 128);
    float acc = 0.f;
    int p = s0;
    for (; p + 1 < s1; p += 2) {
        int sa = csr_src[p], sb = csr_src[p + 1];
        float2 ga = gauss[p], gb = gauss[p + 1];
        float2 va = hk2[(size_t)sa * 64 + lane];
        float2 vb = hk2[(size_t)sb * 64 + lane];
        acc += ga.x * va.x + ga.y * va.y;
        acc += gb.x * vb.x + gb.y * vb.y;
    }
    if (p < s1) {
        int sa = csr_src[p];
        float2 ga = gauss[p];
        float2 va = hk2[(size_t)sa * 64 + lane];
        acc += ga.x * va.x + ga.y * va.y;
    }
    float dg = (float)(s1 - s0);
    if (dg < 1.f) dg = 1.f;
    float val = acc / dg;
    size_t row = (size_t)b * Nn + n;
    float rsum = 0.f;
#pragma unroll
    for (int f = 0; f < F; ++f) rsum += prev[row * F + f] * root[f * 64 + lane];
    val += rsum + bias[lane];
    val = val > 0.f ? val : expm1f(val);
    hout[row * 64 + lane] = val;
    float r = val * fc_w[lane * Ll + l];
#pragma unroll
    for (int off = 32; off; off >>= 1) r += __shfl_down(r, off, 64);
    if (lane == 0) node[row] += r;
}

// ---- head ----------------------------------------------------------------

__global__ void lin1_kernel(const float* __restrict__ node, const float* __restrict__ w,
                            const float* __restrict__ fcb, float* __restrict__ h1acc) {
    int hfc = threadIdx.x;
    int b = blockIdx.y;
    int n0 = blockIdx.x * 64;
    int nend = n0 + 64 < Nn ? n0 + 64 : Nn;
    float fb = fcb[0];
    float acc = 0.f;
    for (int n = n0; n < nend; ++n)
        acc += (node[(size_t)b * Nn + n] + fb) * w[(size_t)n * HFCc + hfc];
    atomicAdd(&h1acc[b * HFCc + hfc], acc);
}

__global__ void head_kernel(const float* __restrict__ h1acc, const float* __restrict__ l1b,
                            const float* __restrict__ w2, const float* __restrict__ b2,
                            float* __restrict__ out) {
    __shared__ float sh[HFCc];
    __shared__ float slog[NCc];
    __shared__ float s_lse;
    int tid = threadIdx.x;
    for (int b = 0; b < BSz; ++b) {
        float v = h1acc[b * HFCc + tid] + l1b[tid];
        v = v > 0.f ? v : expm1f(v);
        sh[tid] = v;
        __syncthreads();
        if (tid < NCc) {
            float s = b2[tid];
            for (int i = 0; i < HFCc; ++i) s += sh[i] * w2[i * NCc + tid];
            slog[tid] = s;
        }
        __syncthreads();
        if (tid == 0) {
            float m = slog[0];
            for (int c = 1; c < NCc; ++c) m = fmaxf(m, slog[c]);
            float se = 0.f;
            for (int c = 0; c < NCc; ++c) se += expf(slog[c] - m);
            s_lse = m + logf(se);
        }
        __syncthreads();
        if (tid < NCc) out[b * NCc + tid] = slog[tid] - s_lse;
        __syncthreads();
    }
}

extern "C" void kernel_launch(void* const* d_in, const int* in_sizes, int n_in,
                              void* d_out, int out_size, void* d_ws, size_t ws_size,
                              hipStream_t stream) {
    const float* x      = (const float*)d_in[0];
    const int*   ei     = (const int*)d_in[2];
    const float* pseudo = (const float*)d_in[3];
    const float* g1     = (const float*)d_in[4];
    const float* mu1    = (const float*)d_in[5];
    const float* sigma1 = (const float*)d_in[6];
    const float* root1  = (const float*)d_in[7];
    const float* b1     = (const float*)d_in[8];
    const float* gs     = (const float*)d_in[9];
    const float* mus    = (const float*)d_in[10];
    const float* sigmas = (const float*)d_in[11];
    const float* roots  = (const float*)d_in[12];
    const float* bs_p   = (const float*)d_in[13];
    const float* fc_w   = (const float*)d_in[14];
    const float* fc_b   = (const float*)d_in[15];
    const float* lin1_w = (const float*)d_in[16];
    const float* lin1_b = (const float*)d_in[17];
    const float* lin2_w = (const float*)d_in[18];
    const float* lin2_b = (const float*)d_in[19];
    float* out = (float*)d_out;

    const int* src = ei;
    const int* dst = ei + Ee;

    auto alignup = [](size_t x) { return (x + 255) & ~(size_t)255; };
    char* ws = (char*)d_ws;
    size_t off = 0;
    float*  node    = (float*)(ws + off);  off += alignup((size_t)BSz * Nn * 4);
    float*  h1acc   = (float*)(ws + off);  off += alignup((size_t)BSz * HFCc * 4);
    int*    offs    = (int*)(ws + off);    off += alignup((size_t)(Nn + 1) * 4);
    int*    cursor  = (int*)(ws + off);    off += alignup((size_t)Nn * 4);
    int*    csr_src = (int*)(ws + off);    off += alignup((size_t)Ee * 4);
    float2* csr_ps  = (float2*)(ws + off); off += alignup((size_t)Ee * 8);
    float2* gauss   = (float2*)(ws + off); off += alignup((size_t)Ll * Ee * 8);
    float*  hk      = (float*)(ws + off);  off += alignup((size_t)BSz * Nn * 128 * 4);
    float*  hA      = (float*)(ws + off);  off += alignup((size_t)BSz * Nn * 64 * 4);
    float*  hB      = (float*)(ws + off);  off += alignup((size_t)BSz * Nn * 64 * 4);
    (void)ws_size; (void)in_sizes; (void)n_in; (void)out_size;

    hipMemsetAsync(node, 0, (size_t)BSz * Nn * 4, stream);
    hipMemsetAsync(h1acc, 0, (size_t)BSz * HFCc * 4, stream);
    hipMemsetAsync(cursor, 0, (size_t)Nn * 4, stream);

    // CSR build (reused across all 4 layers)
    count_kernel<<<(Ee + 255) / 256, 256, 0, stream>>>(dst, cursor);
    scan_kernel<<<1, 256, 0, stream>>>(cursor, offs);
    copy_kernel<<<(Nn + 255) / 256, 256, 0, stream>>>(offs, cursor);
    fill_kernel<<<(Ee + 255) / 256, 256, 0, stream>>>(src, dst, pseudo, cursor, csr_src, csr_ps);
    gauss_kernel<<<(Ee + 255) / 256, 256, 0, stream>>>(csr_ps, mu1, sigma1, mus, sigmas, gauss);

    const float* prev = x;
    float* hnxt = hA;
    float* hother = hB;
    for (int l = 0; l < Ll; ++l) {
        const float* g  = (l == 0) ? g1    : gs    + (size_t)(l - 1) * Hh * 128;
        const float* rt = (l == 0) ? root1 : roots + (size_t)(l - 1) * Hh * Hh;
        const float* bb = (l == 0) ? b1    : bs_p  + (size_t)(l - 1) * Hh;

        if (l == 0)
            transform_kernel<F_INc><<<BSz * Nn, 128, 0, stream>>>(prev, g, hk);
        else
            transform_kernel<Hh><<<BSz * Nn, 128, 0, stream>>>(prev, g, hk);

        dim3 cgrid((Nn + 3) / 4, BSz);
        if (l == 0)
            gather_combine<F_INc><<<cgrid, 256, 0, stream>>>(hk, offs, csr_src,
                gauss + (size_t)l * Ee, prev, rt, bb, fc_w, l, hnxt, node);
        else
            gather_combine<Hh><<<cgrid, 256, 0, stream>>>(hk, offs, csr_src,
                gauss + (size_t)l * Ee, prev, rt, bb, fc_w, l, hnxt, node);

        prev = hnxt;
        float* tmp = hnxt; hnxt = hother; hother = tmp;
    }

    dim3 lgrid((Nn + 63) / 64, BSz);
    lin1_kernel<<<lgrid, 256, 0, stream>>>(node, lin1_w, fc_b, h1acc);

    head_kernel<<<1, HFCc, 0, stream>>>(h1acc, lin1_b, lin2_w, lin2_b, out);
}

// Round 3
// 460.539 us; speedup vs baseline: 4.2548x; 1.1294x over previous
//
#include <hip/hip_runtime.h>
#include <hip/hip_bf16.h>

#define BSz 2
#define Nn 15135
#define Ee 242160
#define F_INc 8
#define Hh 64
#define Ll 4
#define HFCc 256
#define NCc 10
#define EPSg 1e-15f

// ---- CSR build ----------------------------------------------------------

__global__ void count_kernel(const int* __restrict__ dst, int* __restrict__ cnt) {
    int e = blockIdx.x * blockDim.x + threadIdx.x;
    if (e < Ee) atomicAdd(&cnt[dst[e]], 1);
}

// single-block scan: cnt[N] -> offs[N+1], also re-initializes cursor = offs[0..N-1]
__global__ void scan_kernel(const int* __restrict__ cnt, int* __restrict__ offs,
                            int* __restrict__ cursor) {
    __shared__ int swsum[4];
    __shared__ int sbase;
    int tid = threadIdx.x, lane = tid & 63, w = tid >> 6;
    if (tid == 0) sbase = 0;
    __syncthreads();
    for (int c0 = 0; c0 < Nn; c0 += 256) {
        int i = c0 + tid;
        int v = (i < Nn) ? cnt[i] : 0;
        int incl = v;
#pragma unroll
        for (int d = 1; d < 64; d <<= 1) {
            int t = __shfl_up(incl, d, 64);
            if (lane >= d) incl += t;
        }
        if (lane == 63) swsum[w] = incl;
        __syncthreads();
        int wpre = 0;
        for (int ww = 0; ww < w; ++ww) wpre += swsum[ww];
        int base = sbase;
        if (i < Nn) {
            int excl = base + wpre + incl - v;
            offs[i] = excl;
            cursor[i] = excl;
        }
        __syncthreads();
        if (tid == 255) sbase = base + wpre + incl;
        __syncthreads();
    }
    if (tid == 0) offs[Nn] = sbase;
}

// fill CSR slots + per-edge Gaussian weights for all 4 layers, layout gauss[p][l]
__global__ void fill_kernel(const int* __restrict__ src, const int* __restrict__ dst,
                            const float* __restrict__ pseudo, int* __restrict__ cursor,
                            int* __restrict__ csr_src, float2* __restrict__ gauss,
                            const float* __restrict__ mu1, const float* __restrict__ sigma1,
                            const float* __restrict__ mus, const float* __restrict__ sigmas) {
    int e = blockIdx.x * blockDim.x + threadIdx.x;
    if (e >= Ee) return;
    int p = atomicAdd(&cursor[dst[e]], 1);
    csr_src[p] = src[e];
    float2 ps = ((const float2*)pseudo)[e];
#pragma unroll
    for (int l = 0; l < Ll; ++l) {
        const float* mu = (l == 0) ? mu1 : mus + (l - 1) * 4;
        const float* sg = (l == 0) ? sigma1 : sigmas + (l - 1) * 4;
        float d00 = ps.x - mu[0], d01 = ps.y - mu[1];
        float d10 = ps.x - mu[2], d11 = ps.y - mu[3];
        float i00 = 1.f / (EPSg + sg[0] * sg[0]);
        float i01 = 1.f / (EPSg + sg[1] * sg[1]);
        float i10 = 1.f / (EPSg + sg[2] * sg[2]);
        float i11 = 1.f / (EPSg + sg[3] * sg[3]);
        float g0 = expf(-0.5f * (d00 * d00 * i00 + d01 * d01 * i01));
        float g1 = expf(-0.5f * (d10 * d10 * i10 + d11 * d11 * i11));
        gauss[(size_t)p * Ll + l] = make_float2(g0, g1);
    }
}

// ---- per-layer compute ---------------------------------------------------

// thread per (row, h): computes cols h (k=0) and 64+h (k=1), writes interleaved float2.
template<int F>
__global__ void transform_kernel(const float* __restrict__ in, const float* __restrict__ g,
                                 float2* __restrict__ hk2) {
    int tid = threadIdx.x;
    int h = tid & 63;
    int r = tid >> 6;
    int row = blockIdx.x * 4 + r;
    __shared__ float s_in[4][F];
    for (int idx = tid; idx < 4 * F; idx += 256) {
        int rr = idx / F, ff = idx % F;
        int grow = blockIdx.x * 4 + rr;
        s_in[rr][ff] = (grow < BSz * Nn) ? in[(size_t)grow * F + ff] : 0.f;
    }
    __syncthreads();
    if (row >= BSz * Nn) return;
    float a0 = 0.f, a1 = 0.f;
#pragma unroll
    for (int f = 0; f < F; ++f) {
        float iv = s_in[r][f];
        a0 += iv * g[f * 128 + h];
        a1 += iv * g[f * 128 + 64 + h];
    }
    hk2[(size_t)row * 64 + h] = make_float2(a0, a1);
}

// one wave per node, BOTH batches: lane = channel. 4-edge unroll => 8 row loads in flight.
template<int F>
__global__ void gather_combine(const float* __restrict__ hk, const int* __restrict__ offs,
                               const int* __restrict__ csr_src, const float2* __restrict__ gauss,
                               const float* __restrict__ prev, const float* __restrict__ root,
                               const float* __restrict__ bias, const float* __restrict__ fc_w,
                               int l, float* __restrict__ hout, float* __restrict__ node) {
    int tid = threadIdx.x;
    int lane = tid & 63;
    int n = blockIdx.x * 4 + (tid >> 6);
    if (n >= Nn) return;
    int s0 = offs[n], s1 = offs[n + 1];
    const float2* hk0 = (const float2*)hk;
    const float2* hk1 = ((const float2*)hk) + (size_t)Nn * 64;
    float acc0 = 0.f, acc1 = 0.f;
    int p = s0;
    for (; p + 3 < s1; p += 4) {
        int sa = csr_src[p], sb = csr_src[p + 1], sc = csr_src[p + 2], sd = csr_src[p + 3];
        float2 ga = gauss[(size_t)p * Ll + l];
        float2 gb = gauss[(size_t)(p + 1) * Ll + l];
        float2 gc = gauss[(size_t)(p + 2) * Ll + l];
        float2 gd = gauss[(size_t)(p + 3) * Ll + l];
        float2 va0 = hk0[(size_t)sa * 64 + lane];
        float2 va1 = hk1[(size_t)sa * 64 + lane];
        float2 vb0 = hk0[(size_t)sb * 64 + lane];
        float2 vb1 = hk1[(size_t)sb * 64 + lane];
        float2 vc0 = hk0[(size_t)sc * 64 + lane];
        float2 vc1 = hk1[(size_t)sc * 64 + lane];
        float2 vd0 = hk0[(size_t)sd * 64 + lane];
        float2 vd1 = hk1[(size_t)sd * 64 + lane];
        acc0 += ga.x * va0.x + ga.y * va0.y + gb.x * vb0.x + gb.y * vb0.y;
        acc0 += gc.x * vc0.x + gc.y * vc0.y + gd.x * vd0.x + gd.y * vd0.y;
        acc1 += ga.x * va1.x + ga.y * va1.y + gb.x * vb1.x + gb.y * vb1.y;
        acc1 += gc.x * vc1.x + gc.y * vc1.y + gd.x * vd1.x + gd.y * vd1.y;
    }
    for (; p < s1; ++p) {
        int sa = csr_src[p];
        float2 ga = gauss[(size_t)p * Ll + l];
        float2 va0 = hk0[(size_t)sa * 64 + lane];
        float2 va1 = hk1[(size_t)sa * 64 + lane];
        acc0 += ga.x * va0.x + ga.y * va0.y;
        acc1 += ga.x * va1.x + ga.y * va1.y;
    }
    float dg = (float)(s1 - s0);
    if (dg < 1.f) dg = 1.f;
    float inv = 1.f / dg;
    float bv = bias[lane];
    float fw = fc_w[lane * Ll + l];
#pragma unroll
    for (int b = 0; b < BSz; ++b) {
        size_t row = (size_t)b * Nn + n;
        float val = (b == 0 ? acc0 : acc1) * inv;
        float rsum = 0.f;
#pragma unroll
        for (int f = 0; f < F; ++f) rsum += prev[row * F + f] * root[f * 64 + lane];
        val += rsum + bv;
        val = val > 0.f ? val : expm1f(val);
        hout[row * 64 + lane] = val;
        float r = val * fw;
#pragma unroll
        for (int off = 32; off; off >>= 1) r += __shfl_down(r, off, 64);
        if (lane == 0) node[row] = (l == 0) ? r : node[row] + r;
    }
}

// ---- head ----------------------------------------------------------------

__global__ void lin1_kernel(const float* __restrict__ node, const float* __restrict__ w,
                            const float* __restrict__ fcb, float* __restrict__ h1acc) {
    int hfc = threadIdx.x;
    int n0 = blockIdx.x * 64;
    int nend = n0 + 64 < Nn ? n0 + 64 : Nn;
    float fb = fcb[0];
    float a0 = 0.f, a1 = 0.f;
    for (int n = n0; n < nend; ++n) {
        float wv = w[(size_t)n * HFCc + hfc];
        a0 += (node[n] + fb) * wv;
        a1 += (node[Nn + n] + fb) * wv;
    }
    atomicAdd(&h1acc[hfc], a0);
    atomicAdd(&h1acc[HFCc + hfc], a1);
}

__global__ void head_kernel(const float* __restrict__ h1acc, const float* __restrict__ l1b,
                            const float* __restrict__ w2, const float* __restrict__ b2,
                            float* __restrict__ out) {
    __shared__ float sh[HFCc];
    __shared__ float slog[NCc];
    __shared__ float s_lse;
    int tid = threadIdx.x;
    for (int b = 0; b < BSz; ++b) {
        float v = h1acc[b * HFCc + tid] + l1b[tid];
        v = v > 0.f ? v : expm1f(v);
        sh[tid] = v;
        __syncthreads();
        if (tid < NCc) {
            float s = b2[tid];
            for (int i = 0; i < HFCc; ++i) s += sh[i] * w2[i * NCc + tid];
            slog[tid] = s;
        }
        __syncthreads();
        if (tid == 0) {
            float m = slog[0];
            for (int c = 1; c < NCc; ++c) m = fmaxf(m, slog[c]);
            float se = 0.f;
            for (int c = 0; c < NCc; ++c) se += expf(slog[c] - m);
            s_lse = m + logf(se);
        }
        __syncthreads();
        if (tid < NCc) out[b * NCc + tid] = slog[tid] - s_lse;
        __syncthreads();
    }
}

extern "C" void kernel_launch(void* const* d_in, const int* in_sizes, int n_in,
                              void* d_out, int out_size, void* d_ws, size_t ws_size,
                              hipStream_t stream) {
    const float* x      = (const float*)d_in[0];
    const int*   ei     = (const int*)d_in[2];
    const float* pseudo = (const float*)d_in[3];
    const float* g1     = (const float*)d_in[4];
    const float* mu1    = (const float*)d_in[5];
    const float* sigma1 = (const float*)d_in[6];
    const float* root1  = (const float*)d_in[7];
    const float* b1     = (const float*)d_in[8];
    const float* gs     = (const float*)d_in[9];
    const float* mus    = (const float*)d_in[10];
    const float* sigmas = (const float*)d_in[11];
    const float* roots  = (const float*)d_in[12];
    const float* bs_p   = (const float*)d_in[13];
    const float* fc_w   = (const float*)d_in[14];
    const float* fc_b   = (const float*)d_in[15];
    const float* lin1_w = (const float*)d_in[16];
    const float* lin1_b = (const float*)d_in[17];
    const float* lin2_w = (const float*)d_in[18];
    const float* lin2_b = (const float*)d_in[19];
    float* out = (float*)d_out;

    const int* src = ei;
    const int* dst = ei + Ee;

    auto alignup = [](size_t x) { return (x + 255) & ~(size_t)255; };
    char* ws = (char*)d_ws;
    size_t off = 0;
    float*  node    = (float*)(ws + off);  off += alignup((size_t)BSz * Nn * 4);
    float*  h1acc   = (float*)(ws + off);  off += alignup((size_t)BSz * HFCc * 4);
    int*    offs    = (int*)(ws + off);    off += alignup((size_t)(Nn + 1) * 4);
    int*    cursor  = (int*)(ws + off);    off += alignup((size_t)Nn * 4);
    int*    csr_src = (int*)(ws + off);    off += alignup((size_t)Ee * 4);
    float2* gauss   = (float2*)(ws + off); off += alignup((size_t)Ee * Ll * 8);
    float*  hk      = (float*)(ws + off);  off += alignup((size_t)BSz * Nn * 128 * 4);
    float*  hA      = (float*)(ws + off);  off += alignup((size_t)BSz * Nn * 64 * 4);
    float*  hB      = (float*)(ws + off);  off += alignup((size_t)BSz * Nn * 64 * 4);
    (void)ws_size; (void)in_sizes; (void)n_in; (void)out_size;

    hipMemsetAsync(cursor, 0, (size_t)Nn * 4, stream);
    hipMemsetAsync(h1acc, 0, (size_t)BSz * HFCc * 4, stream);

    count_kernel<<<(Ee + 255) / 256, 256, 0, stream>>>(dst, cursor);
    scan_kernel<<<1, 256, 0, stream>>>(cursor, offs, cursor);
    fill_kernel<<<(Ee + 255) / 256, 256, 0, stream>>>(src, dst, pseudo, cursor, csr_src, gauss,
                                                      mu1, sigma1, mus, sigmas);

    const float* prev = x;
    float* hnxt = hA;
    float* hother = hB;
    for (int l = 0; l < Ll; ++l) {
        const float* g  = (l == 0) ? g1    : gs    + (size_t)(l - 1) * Hh * 128;
        const float* rt = (l == 0) ? root1 : roots + (size_t)(l - 1) * Hh * Hh;
        const float* bb = (l == 0) ? b1    : bs_p  + (size_t)(l - 1) * Hh;

        int tgrid = (BSz * Nn + 3) / 4;
        if (l == 0)
            transform_kernel<F_INc><<<tgrid, 256, 0, stream>>>(prev, g, (float2*)hk);
        else
            transform_kernel<Hh><<<tgrid, 256, 0, stream>>>(prev, g, (float2*)hk);

        int cgrid = (Nn + 3) / 4;
        if (l == 0)
            gather_combine<F_INc><<<cgrid, 256, 0, stream>>>(hk, offs, csr_src, gauss,
                prev, rt, bb, fc_w, l, hnxt, node);
        else
            gather_combine<Hh><<<cgrid, 256, 0, stream>>>(hk, offs, csr_src, gauss,
                prev, rt, bb, fc_w, l, hnxt, node);

        prev = hnxt;
        float* tmp = hnxt; hnxt = hother; hother = tmp;
    }

    lin1_kernel<<<(Nn + 63) / 64, 256, 0, stream>>>(node, lin1_w, fc_b, h1acc);

    head_kernel<<<1, HFCc, 0, stream>>>(h1acc, lin1_b, lin2_w, lin2_b, out);
}